// Round 3
// baseline (345.792 us; speedup 1.0000x reference)
//
#include <hip/hip_runtime.h>
#include <stdint.h>

#define S_   512
#define E_   512
#define CIN  1536
#define P_   32768
#define OUTC 512
#define LDP  40   // padded LDS row stride (shorts); 80B row -> worst 2-way bank alias (free)

typedef __attribute__((ext_vector_type(8))) short s16x8;   // MFMA A/B frag (8 bf16) per guide
typedef __attribute__((ext_vector_type(4))) float f32x4;   // MFMA C/D frag

__device__ __forceinline__ float b2f(uint32_t b) {
    union { uint32_t u; float f; } v; v.u = b << 16; return v.f;
}
__device__ __forceinline__ uint32_t f2b(float f) {   // fp32 -> bf16 bits, RNE
    union { float f; uint32_t u; } v; v.f = f;
    return (v.u + 0x7fffu + ((v.u >> 16) & 1u)) >> 16;
}

// ---------- 0) dtype probe (g1 is all-ones) + zero the stats accumulators ----------
__global__ void probe_zero(const uint32_t* __restrict__ g1w, int* __restrict__ flag,
                           float* __restrict__ stats)
{
    const int t = threadIdx.x;           // 1024 threads
    stats[t] = 0.f; stats[t + 1024] = 0.f;
    if (t == 0) *flag = (g1w[0] == 0x3F803F80u) ? 1 : 0;   // 1 = bf16 wire, 0 = fp32 wire
}

// ---------- 0b) ingest: wire dtype -> canonical (bf16 for H/W, fp32 for small tensors) ----------
struct Ing {
    const void* src[11];
    void*       dst[11];
    int         n[11];
    int         of32[11];
};
__global__ __launch_bounds__(256) void ingest_kernel(Ing d, const int* __restrict__ flag)
{
    const int ti = blockIdx.y;
    const int n  = d.n[ti];
    const int e  = (blockIdx.x * 256 + threadIdx.x) * 4;
    if (e >= n) return;
    const int inb = *flag;
    float x[4];
    if (inb) {
        const uint16_t* s = (const uint16_t*)d.src[ti];
#pragma unroll
        for (int i = 0; i < 4; ++i) x[i] = b2f(s[e + i]);
    } else {
        const float* s = (const float*)d.src[ti];
#pragma unroll
        for (int i = 0; i < 4; ++i) x[i] = s[e + i];
    }
    if (d.of32[ti]) {
        float* o = (float*)d.dst[ti];
#pragma unroll
        for (int i = 0; i < 4; ++i) o[e + i] = x[i];
    } else {
        uint16_t* o = (uint16_t*)d.dst[ti];
#pragma unroll
        for (int i = 0; i < 4; ++i) o[e + i] = (uint16_t)f2b(x[i]);
    }
}

// ---------- 1) kNN: 3 nearest centers + inverse-distance weights (fp32 canonical) ----------
__global__ __launch_bounds__(256) void knn_kernel(
    const float* __restrict__ xyz, const float* __restrict__ centers,
    int* __restrict__ idx_out, float* __restrict__ w_out)
{
    __shared__ float cx[S_], cy[S_], cz[S_], cc[S_];
    const int t = threadIdx.x;
    const int p = blockIdx.x * 256 + t;      // 256 | 8192 -> one batch per block
    const int b = p >> 13;
    for (int i = t; i < S_; i += 256) {
        const float x = centers[(size_t)(b * S_ + i) * 3 + 0];
        const float y = centers[(size_t)(b * S_ + i) * 3 + 1];
        const float z = centers[(size_t)(b * S_ + i) * 3 + 2];
        cx[i] = x; cy[i] = y; cz[i] = z; cc[i] = x * x + y * y + z * z;
    }
    __syncthreads();

    const float x = xyz[(size_t)p * 3 + 0];
    const float y = xyz[(size_t)p * 3 + 1];
    const float z = xyz[(size_t)p * 3 + 2];
    const float xx = x * x + y * y + z * z;

    float d0 = 3e38f, d1 = 3e38f, d2 = 3e38f;
    int   i0 = 0,     i1 = 0,     i2 = 0;
    for (int s = 0; s < S_; ++s) {
        const float dot = x * cx[s] + y * cy[s] + z * cz[s];
        const float d = (xx - 2.0f * dot) + cc[s];
        if (d < d2) {
            if (d < d1) {
                if (d < d0) { d2 = d1; i2 = i1; d1 = d0; i1 = i0; d0 = d; i0 = s; }
                else        { d2 = d1; i2 = i1; d1 = d;  i1 = s; }
            } else          { d2 = d;  i2 = s; }
        }
    }
    const float r0 = 1.0f / (d0 + 1e-8f);
    const float r1 = 1.0f / (d1 + 1e-8f);
    const float r2 = 1.0f / (d2 + 1e-8f);
    const float rs = r0 + r1 + r2;
    idx_out[p * 3 + 0] = i0; idx_out[p * 3 + 1] = i1; idx_out[p * 3 + 2] = i2;
    w_out[p * 3 + 0] = r0 / rs; w_out[p * 3 + 1] = r1 / rs; w_out[p * 3 + 2] = r2 / rs;
}

// ---------- 2) G[b] = concat(H4,H8,H12)[b] (512x1536) x W1^T -> fp32 [4,512,512] ----------
__global__ __launch_bounds__(256) void gemm_g(
    const uint16_t* __restrict__ H4c, const uint16_t* __restrict__ H8c,
    const uint16_t* __restrict__ H12c, const uint16_t* __restrict__ W1c,
    float* __restrict__ G)
{
    __shared__ uint16_t Asm[128 * LDP];
    __shared__ uint16_t Bsm[128 * LDP];
    const int t = threadIdx.x, wave = t >> 6, lane = t & 63;
    const int wr = wave >> 1, wc = wave & 1, quad = lane >> 4, l15 = lane & 15;
    const int bb = blockIdx.z;
    const int colBase = blockIdx.x * 128, rowBase = blockIdx.y * 128;

    f32x4 acc[4][4];
    const f32x4 z4 = {0.f, 0.f, 0.f, 0.f};
#pragma unroll
    for (int i = 0; i < 4; ++i)
#pragma unroll
        for (int j = 0; j < 4; ++j) acc[i][j] = z4;

    const int ar = t >> 2, ac = (t & 3) * 8;    // rows 0..63 (slot0), +64 (slot1)
    const size_t hb = (size_t)bb * S_ * E_;

    for (int k0 = 0; k0 < CIN; k0 += 32) {
        const uint16_t* Hs = ((k0 < 512) ? H4c : (k0 < 1024) ? H8c : H12c) + hb + (k0 & 511);
        const uint4 a0 = *(const uint4*)(Hs + (size_t)(rowBase + ar) * E_ + ac);
        const uint4 a1 = *(const uint4*)(Hs + (size_t)(rowBase + ar + 64) * E_ + ac);
        const uint4 b0 = *(const uint4*)(W1c + (size_t)(colBase + ar) * CIN + k0 + ac);
        const uint4 b1 = *(const uint4*)(W1c + (size_t)(colBase + ar + 64) * CIN + k0 + ac);
        __syncthreads();
        *(uint4*)&Asm[ar * LDP + ac] = a0;
        *(uint4*)&Asm[(ar + 64) * LDP + ac] = a1;
        *(uint4*)&Bsm[ar * LDP + ac] = b0;
        *(uint4*)&Bsm[(ar + 64) * LDP + ac] = b1;
        __syncthreads();

        s16x8 af[4], bfr[4];
#pragma unroll
        for (int mi = 0; mi < 4; ++mi)
            af[mi] = *(const s16x8*)&Asm[(wr * 64 + mi * 16 + l15) * LDP + quad * 8];
#pragma unroll
        for (int ni = 0; ni < 4; ++ni)
            bfr[ni] = *(const s16x8*)&Bsm[(wc * 64 + ni * 16 + l15) * LDP + quad * 8];
#pragma unroll
        for (int mi = 0; mi < 4; ++mi)
#pragma unroll
            for (int ni = 0; ni < 4; ++ni)
                acc[mi][ni] = __builtin_amdgcn_mfma_f32_16x16x32_bf16(
                    af[mi], bfr[ni], acc[mi][ni], 0, 0, 0);
    }

#pragma unroll
    for (int mi = 0; mi < 4; ++mi) {
        const int row0 = rowBase + wr * 64 + mi * 16 + quad * 4;
#pragma unroll
        for (int ni = 0; ni < 4; ++ni) {
            const int col = colBase + wc * 64 + ni * 16 + l15;
#pragma unroll
            for (int r = 0; r < 4; ++r)
                G[((size_t)bb * S_ + row0 + r) * OUTC + col] = acc[mi][ni][r];
        }
    }
}

// ---------- 3) blend: C1[p] = sum_k w_k * G[b, i_k]  (fp32 math) + BN1 stats ----------
__global__ __launch_bounds__(256) void blend1(
    const float* __restrict__ G, const int* __restrict__ idx, const float* __restrict__ wgt,
    uint16_t* __restrict__ C1, float* __restrict__ gsum, float* __restrict__ gsq)
{
    __shared__ float reds[512], redq[512];
    const int t = threadIdx.x;
    const int cg = t & 63, pr = t >> 6;
    const int ch0 = cg * 8;
    const int pBase = blockIdx.x * 256;

    float s[8], q[8];
#pragma unroll
    for (int e = 0; e < 8; ++e) { s[e] = 0.f; q[e] = 0.f; }

    for (int j = 0; j < 64; ++j) {
        const int p = pBase + j * 4 + pr;
        const int b = p >> 13;
        const int i0 = idx[p * 3 + 0], i1 = idx[p * 3 + 1], i2 = idx[p * 3 + 2];
        const float w0 = wgt[p * 3 + 0], w1 = wgt[p * 3 + 1], w2 = wgt[p * 3 + 2];
        const float* g0 = G + ((size_t)b * S_ + i0) * OUTC + ch0;
        const float* g1 = G + ((size_t)b * S_ + i1) * OUTC + ch0;
        const float* g2 = G + ((size_t)b * S_ + i2) * OUTC + ch0;
        float c[8];
        uint32_t od[4];
#pragma unroll
        for (int e = 0; e < 8; ++e) {
            c[e] = w0 * g0[e] + w1 * g1[e] + w2 * g2[e];
            s[e] += c[e]; q[e] += c[e] * c[e];
        }
#pragma unroll
        for (int e = 0; e < 4; ++e) od[e] = f2b(c[2 * e]) | (f2b(c[2 * e + 1]) << 16);
        uint4 o; o.x = od[0]; o.y = od[1]; o.z = od[2]; o.w = od[3];
        *(uint4*)(C1 + (size_t)p * OUTC + ch0) = o;
    }

    for (int i = t; i < 512; i += 256) { reds[i] = 0.f; redq[i] = 0.f; }
    __syncthreads();
#pragma unroll
    for (int e = 0; e < 8; ++e) {
        atomicAdd(&reds[ch0 + e], s[e]);
        atomicAdd(&redq[ch0 + e], q[e]);
    }
    __syncthreads();
    for (int i = t; i < 512; i += 256) {
        atomicAdd(&gsum[i], reds[i]);
        atomicAdd(&gsq[i],  redq[i]);
    }
}

// ---------- 4) BN finalize ----------
__global__ void bn_finalize(const float* __restrict__ gsum, const float* __restrict__ gsq,
                            const float* __restrict__ gamma, const float* __restrict__ beta,
                            float* __restrict__ ss)
{
    const int c = threadIdx.x;   // 512
    const float inv  = 1.0f / (float)P_;
    const float mean = gsum[c] * inv;
    const float var  = gsq[c] * inv - mean * mean;
    const float sc   = gamma[c] * rsqrtf(var + 1e-5f);
    ss[c]       = sc;
    ss[512 + c] = beta[c] - mean * sc;
}

// ---------- 5) BN apply + ReLU on canonical bf16 C1 (in place) ----------
__global__ __launch_bounds__(256) void bn_apply_c1(
    uint16_t* __restrict__ X, const float* __restrict__ ss)
{
    __shared__ float sc[512], sh[512];
    const int t = threadIdx.x;
    for (int i = t; i < 512; i += 256) { sc[i] = ss[i]; sh[i] = ss[512 + i]; }
    __syncthreads();
    const size_t v = (size_t)blockIdx.x * 256 + t;
    uint4 xv = ((const uint4*)X)[v];
    const int ch = (int)((v * 8) & 511);
    uint32_t wsrc[4] = {xv.x, xv.y, xv.z, xv.w};
    uint32_t od[4];
#pragma unroll
    for (int j = 0; j < 4; ++j) {
        const int c0 = ch + 2 * j;
        const float y0 = fmaxf(0.f, b2f(wsrc[j] & 0xffffu) * sc[c0]     + sh[c0]);
        const float y1 = fmaxf(0.f, b2f(wsrc[j] >> 16)     * sc[c0 + 1] + sh[c0 + 1]);
        od[j] = f2b(y0) | (f2b(y1) << 16);
    }
    uint4 o; o.x = od[0]; o.y = od[1]; o.z = od[2]; o.w = od[3];
    ((uint4*)X)[v] = o;
}

// ---------- 6) GEMM2: C1 x W2^T -> d_out (wire dtype) + BN2 stats ----------
__global__ __launch_bounds__(256) void gemm2_stats(
    const uint16_t* __restrict__ A, const uint16_t* __restrict__ Bw,
    void* __restrict__ Cout, const int* __restrict__ flag,
    float* __restrict__ gsum, float* __restrict__ gsq)
{
    __shared__ uint16_t Asm[128 * LDP];
    __shared__ uint16_t Bsm[128 * LDP];
    __shared__ float red[256];
    const int K = 512, Nn = 512;
    const int t = threadIdx.x, wave = t >> 6, lane = t & 63;
    const int wr = wave >> 1, wc = wave & 1, quad = lane >> 4, l15 = lane & 15;
    const int colBase = blockIdx.x * 128, rowBase = blockIdx.y * 128;
    const int outBf16 = *flag;

    f32x4 acc[4][4];
    const f32x4 z4 = {0.f, 0.f, 0.f, 0.f};
#pragma unroll
    for (int i = 0; i < 4; ++i)
#pragma unroll
        for (int j = 0; j < 4; ++j) acc[i][j] = z4;

    const int ar = t >> 2, ac = (t & 3) * 8;

    for (int k0 = 0; k0 < K; k0 += 32) {
        const uint4 a0 = *(const uint4*)(A  + (size_t)(rowBase + ar) * K + k0 + ac);
        const uint4 a1 = *(const uint4*)(A  + (size_t)(rowBase + ar + 64) * K + k0 + ac);
        const uint4 b0 = *(const uint4*)(Bw + (size_t)(colBase + ar) * K + k0 + ac);
        const uint4 b1 = *(const uint4*)(Bw + (size_t)(colBase + ar + 64) * K + k0 + ac);
        __syncthreads();
        *(uint4*)&Asm[ar * LDP + ac] = a0;
        *(uint4*)&Asm[(ar + 64) * LDP + ac] = a1;
        *(uint4*)&Bsm[ar * LDP + ac] = b0;
        *(uint4*)&Bsm[(ar + 64) * LDP + ac] = b1;
        __syncthreads();

        s16x8 af[4], bfr[4];
#pragma unroll
        for (int mi = 0; mi < 4; ++mi)
            af[mi] = *(const s16x8*)&Asm[(wr * 64 + mi * 16 + l15) * LDP + quad * 8];
#pragma unroll
        for (int ni = 0; ni < 4; ++ni)
            bfr[ni] = *(const s16x8*)&Bsm[(wc * 64 + ni * 16 + l15) * LDP + quad * 8];
#pragma unroll
        for (int mi = 0; mi < 4; ++mi)
#pragma unroll
            for (int ni = 0; ni < 4; ++ni)
                acc[mi][ni] = __builtin_amdgcn_mfma_f32_16x16x32_bf16(
                    af[mi], bfr[ni], acc[mi][ni], 0, 0, 0);
    }

    // BN2 stats
    red[t] = 0.f;
    __syncthreads();
#pragma unroll
    for (int ni = 0; ni < 4; ++ni) {
        float s = 0.f, q = 0.f;
#pragma unroll
        for (int mi = 0; mi < 4; ++mi)
#pragma unroll
            for (int r = 0; r < 4; ++r) { const float v = acc[mi][ni][r]; s += v; q += v * v; }
        const int cl = wc * 64 + ni * 16 + l15;
        atomicAdd(&red[cl], s);
        atomicAdd(&red[128 + cl], q);
    }
    __syncthreads();
    if (t < 128) atomicAdd(&gsum[colBase + t], red[t]);
    else         atomicAdd(&gsq[colBase + (t - 128)], red[t]);

    // store in wire dtype. D layout: col(N)=lane&15, row(M)=quad*4+reg
    if (outBf16) {
        uint16_t* Cs = (uint16_t*)Cout;
#pragma unroll
        for (int mi = 0; mi < 4; ++mi) {
            const int row0 = rowBase + wr * 64 + mi * 16 + quad * 4;
#pragma unroll
            for (int ni = 0; ni < 4; ++ni) {
                const int col = colBase + wc * 64 + ni * 16 + l15;
#pragma unroll
                for (int r = 0; r < 4; ++r)
                    Cs[(size_t)(row0 + r) * Nn + col] = (uint16_t)f2b(acc[mi][ni][r]);
            }
        }
    } else {
        float* Cf = (float*)Cout;
#pragma unroll
        for (int mi = 0; mi < 4; ++mi) {
            const int row0 = rowBase + wr * 64 + mi * 16 + quad * 4;
#pragma unroll
            for (int ni = 0; ni < 4; ++ni) {
                const int col = colBase + wc * 64 + ni * 16 + l15;
#pragma unroll
                for (int r = 0; r < 4; ++r)
                    Cf[(size_t)(row0 + r) * Nn + col] = acc[mi][ni][r];
            }
        }
    }
}

// ---------- 7) BN apply + ReLU on d_out (wire dtype, in place) ----------
__global__ __launch_bounds__(256) void bn_apply_out(
    void* __restrict__ X, const float* __restrict__ ss, const int* __restrict__ flag)
{
    __shared__ float sc[512], sh[512];
    const int t = threadIdx.x;
    for (int i = t; i < 512; i += 256) { sc[i] = ss[i]; sh[i] = ss[512 + i]; }
    __syncthreads();
    const size_t v = (size_t)blockIdx.x * 256 + t;   // 8 elements per thread
    const int ch = (int)((v * 8) & 511);
    if (*flag) {
        uint4 xv = ((const uint4*)X)[v];
        uint32_t wsrc[4] = {xv.x, xv.y, xv.z, xv.w};
        uint32_t od[4];
#pragma unroll
        for (int j = 0; j < 4; ++j) {
            const int c0 = ch + 2 * j;
            const float y0 = fmaxf(0.f, b2f(wsrc[j] & 0xffffu) * sc[c0]     + sh[c0]);
            const float y1 = fmaxf(0.f, b2f(wsrc[j] >> 16)     * sc[c0 + 1] + sh[c0 + 1]);
            od[j] = f2b(y0) | (f2b(y1) << 16);
        }
        uint4 o; o.x = od[0]; o.y = od[1]; o.z = od[2]; o.w = od[3];
        ((uint4*)X)[v] = o;
    } else {
        float4* Xf = (float4*)X;
        float4 u0 = Xf[v * 2], u1 = Xf[v * 2 + 1];
        u0.x = fmaxf(0.f, u0.x * sc[ch + 0] + sh[ch + 0]);
        u0.y = fmaxf(0.f, u0.y * sc[ch + 1] + sh[ch + 1]);
        u0.z = fmaxf(0.f, u0.z * sc[ch + 2] + sh[ch + 2]);
        u0.w = fmaxf(0.f, u0.w * sc[ch + 3] + sh[ch + 3]);
        u1.x = fmaxf(0.f, u1.x * sc[ch + 4] + sh[ch + 4]);
        u1.y = fmaxf(0.f, u1.y * sc[ch + 5] + sh[ch + 5]);
        u1.z = fmaxf(0.f, u1.z * sc[ch + 6] + sh[ch + 6]);
        u1.w = fmaxf(0.f, u1.w * sc[ch + 7] + sh[ch + 7]);
        Xf[v * 2] = u0; Xf[v * 2 + 1] = u1;
    }
}

// ---------- launch ----------
extern "C" void kernel_launch(void* const* d_in, const int* in_sizes, int n_in,
                              void* d_out, int out_size, void* d_ws, size_t ws_size,
                              hipStream_t stream)
{
    (void)in_sizes; (void)n_in; (void)out_size; (void)ws_size;
    // setup_inputs order: xyz, centers, H4, H8, H12, W1, b1, g1, beta1, W2, b2, g2, beta2
    const void* xyz_w = d_in[0];  const void* cen_w = d_in[1];
    const void* H4w = d_in[2];    const void* H8w = d_in[3];   const void* H12w = d_in[4];
    const void* W1w = d_in[5];    /* b1 = d_in[6] cancels in BN */
    const void* g1w = d_in[7];    const void* be1w = d_in[8];
    const void* W2w = d_in[9];    /* b2 = d_in[10] cancels */
    const void* g2w = d_in[11];   const void* be2w = d_in[12];

    char* w = (char*)d_ws;
    int*      flag  = (int*)w;       w += 16;
    float*    stats = (float*)w;     w += 2048 * 4;      // sum1,sq1,sum2,sq2
    float*    ss1   = (float*)w;     w += 1024 * 4;
    float*    ss2   = (float*)w;     w += 1024 * 4;
    float*    xyzF  = (float*)w;     w += (size_t)P_ * 3 * 4;
    float*    cenF  = (float*)w;     w += (size_t)4 * S_ * 3 * 4;
    float*    g1F   = (float*)w;     w += 512 * 4;
    float*    be1F  = (float*)w;     w += 512 * 4;
    float*    g2F   = (float*)w;     w += 512 * 4;
    float*    be2F  = (float*)w;     w += 512 * 4;
    uint16_t* Hc4   = (uint16_t*)w;  w += (size_t)4 * S_ * E_ * 2;
    uint16_t* Hc8   = (uint16_t*)w;  w += (size_t)4 * S_ * E_ * 2;
    uint16_t* Hc12  = (uint16_t*)w;  w += (size_t)4 * S_ * E_ * 2;
    uint16_t* W1c   = (uint16_t*)w;  w += (size_t)OUTC * CIN * 2;
    uint16_t* W2c   = (uint16_t*)w;  w += (size_t)OUTC * OUTC * 2;
    int*      idxb  = (int*)w;       w += (size_t)P_ * 3 * 4;
    float*    wb    = (float*)w;     w += (size_t)P_ * 3 * 4;
    float*    G     = (float*)w;     w += (size_t)4 * S_ * OUTC * 4;   // 4 MB fp32
    uint16_t* C1    = (uint16_t*)w;  w += (size_t)P_ * OUTC * 2;       // 32 MB
    float* sum1 = stats, *sq1 = stats + 512, *sum2 = stats + 1024, *sq2 = stats + 1536;

    Ing ing;
    const void* srcs[11] = {H4w, H8w, H12w, W1w, W2w, xyz_w, cen_w, g1w, be1w, g2w, be2w};
    void* dsts[11] = {Hc4, Hc8, Hc12, W1c, W2c, xyzF, cenF, g1F, be1F, g2F, be2F};
    const int ns[11] = {4*S_*E_, 4*S_*E_, 4*S_*E_, OUTC*CIN, OUTC*OUTC,
                        P_*3, 4*S_*3, 512, 512, 512, 512};
    const int of32s[11] = {0,0,0,0,0, 1,1,1,1,1,1};
    for (int i = 0; i < 11; ++i) {
        ing.src[i] = srcs[i]; ing.dst[i] = dsts[i]; ing.n[i] = ns[i]; ing.of32[i] = of32s[i];
    }

    probe_zero<<<1, 1024, 0, stream>>>((const uint32_t*)g1w, flag, stats);
    ingest_kernel<<<dim3(1024, 11), 256, 0, stream>>>(ing, flag);
    knn_kernel<<<P_ / 256, 256, 0, stream>>>(xyzF, cenF, idxb, wb);
    gemm_g<<<dim3(4, 4, 4), 256, 0, stream>>>(Hc4, Hc8, Hc12, W1c, G);
    blend1<<<P_ / 256, 256, 0, stream>>>(G, idxb, wb, C1, sum1, sq1);
    bn_finalize<<<1, 512, 0, stream>>>(sum1, sq1, g1F, be1F, ss1);
    bn_apply_c1<<<(P_ * OUTC / 8) / 256, 256, 0, stream>>>(C1, ss1);
    gemm2_stats<<<dim3(4, P_ / 128), 256, 0, stream>>>(C1, W2c, d_out, flag, sum2, sq2);
    bn_finalize<<<1, 512, 0, stream>>>(sum2, sq2, g2F, be2F, ss2);
    bn_apply_out<<<(P_ * OUTC / 8) / 256, 256, 0, stream>>>(d_out, ss2, flag);
}

// Round 4
// 308.370 us; speedup vs baseline: 1.1214x; 1.1214x over previous
//
#include <hip/hip_runtime.h>
#include <stdint.h>

#define S_   512
#define E_   512
#define CIN  1536
#define P_   32768
#define OUTC 512
#define LDP  40   // padded LDS stride for register-staged gemm_g (80B -> 2-way max, free)

typedef __attribute__((ext_vector_type(8))) short s16x8;   // MFMA A/B frag (8 bf16)
typedef __attribute__((ext_vector_type(4))) float f32x4;   // MFMA C/D frag
typedef unsigned short ushort_t;

__device__ __forceinline__ float b2f(uint32_t b) {
    union { uint32_t u; float f; } v; v.u = b << 16; return v.f;
}
__device__ __forceinline__ uint32_t f2b(float f) {   // fp32 -> bf16 bits, RNE
    union { float f; uint32_t u; } v; v.f = f;
    return (v.u + 0x7fffu + ((v.u >> 16) & 1u)) >> 16;
}
__device__ __forceinline__ uint4 cvt8(float4 a, float4 b) {
    uint4 r;
    r.x = f2b(a.x) | (f2b(a.y) << 16);
    r.y = f2b(a.z) | (f2b(a.w) << 16);
    r.z = f2b(b.x) | (f2b(b.y) << 16);
    r.w = f2b(b.z) | (f2b(b.w) << 16);
    return r;
}
__device__ __forceinline__ void async16(const void* g, void* l) {
    __builtin_amdgcn_global_load_lds(
        (const __attribute__((address_space(1))) void*)g,
        (__attribute__((address_space(3))) void*)l, 16, 0, 0);
}

// ---------- 0) prep: W1,W2 fp32 -> bf16 ----------
__global__ __launch_bounds__(256) void prep_w(
    const float* __restrict__ W1f, const float* __restrict__ W2f,
    ushort_t* __restrict__ W1c, ushort_t* __restrict__ W2c)
{
    int v = blockIdx.x * 256 + threadIdx.x;          // vec4 index
    if (v < (OUTC * CIN / 4)) {
        const float4 x = ((const float4*)W1f)[v];
        uint2 o; o.x = f2b(x.x) | (f2b(x.y) << 16); o.y = f2b(x.z) | (f2b(x.w) << 16);
        ((uint2*)W1c)[v] = o;
    } else {
        v -= OUTC * CIN / 4;
        const float4 x = ((const float4*)W2f)[v];
        uint2 o; o.x = f2b(x.x) | (f2b(x.y) << 16); o.y = f2b(x.z) | (f2b(x.w) << 16);
        ((uint2*)W2c)[v] = o;
    }
}

// ---------- 1) kNN (fp32 wire direct) ----------
__global__ __launch_bounds__(128) void knn_kernel(
    const float* __restrict__ xyz, const float* __restrict__ centers,
    int* __restrict__ idx_out, float* __restrict__ w_out)
{
    __shared__ float cx[S_], cy[S_], cz[S_], cc[S_];
    const int t = threadIdx.x;
    const int p = blockIdx.x * 128 + t;      // 128 | 8192 -> one batch per block
    const int b = p >> 13;
    for (int i = t; i < S_; i += 128) {
        const float x = centers[(size_t)(b * S_ + i) * 3 + 0];
        const float y = centers[(size_t)(b * S_ + i) * 3 + 1];
        const float z = centers[(size_t)(b * S_ + i) * 3 + 2];
        cx[i] = x; cy[i] = y; cz[i] = z; cc[i] = x * x + y * y + z * z;
    }
    __syncthreads();

    const float x = xyz[(size_t)p * 3 + 0];
    const float y = xyz[(size_t)p * 3 + 1];
    const float z = xyz[(size_t)p * 3 + 2];
    const float xx = x * x + y * y + z * z;

    float d0 = 3e38f, d1 = 3e38f, d2 = 3e38f;
    int   i0 = 0,     i1 = 0,     i2 = 0;
    for (int s = 0; s < S_; ++s) {
        const float dot = x * cx[s] + y * cy[s] + z * cz[s];
        const float d = (xx - 2.0f * dot) + cc[s];   // mirror np association
        if (d < d2) {
            if (d < d1) {
                if (d < d0) { d2 = d1; i2 = i1; d1 = d0; i1 = i0; d0 = d; i0 = s; }
                else        { d2 = d1; i2 = i1; d1 = d;  i1 = s; }
            } else          { d2 = d;  i2 = s; }
        }
    }
    const float r0 = 1.0f / (d0 + 1e-8f);
    const float r1 = 1.0f / (d1 + 1e-8f);
    const float r2 = 1.0f / (d2 + 1e-8f);
    const float rs = r0 + r1 + r2;
    idx_out[p * 3 + 0] = i0; idx_out[p * 3 + 1] = i1; idx_out[p * 3 + 2] = i2;
    w_out[p * 3 + 0] = r0 / rs; w_out[p * 3 + 1] = r1 / rs; w_out[p * 3 + 2] = r2 / rs;
}

// ---------- 2) G[b] = concat(H)[b](512x1536 fp32) x W1c^T -> fp32 [4,512,512] ----------
// Register double-buffer prefetch (1 block/CU -> latency-bound without it).
__global__ __launch_bounds__(256) void gemm_g(
    const float* __restrict__ H4, const float* __restrict__ H8,
    const float* __restrict__ H12, const ushort_t* __restrict__ W1c,
    float* __restrict__ G)
{
    __shared__ ushort_t Asm[128 * LDP];
    __shared__ ushort_t Bsm[128 * LDP];
    const int t = threadIdx.x, wave = t >> 6, lane = t & 63;
    const int wr = wave >> 1, wc = wave & 1, quad = lane >> 4, l15 = lane & 15;
    const int bb = blockIdx.z;
    const int colBase = blockIdx.x * 128, rowBase = blockIdx.y * 128;
    const size_t hb = (size_t)bb * S_ * E_;

    f32x4 acc[4][4];
    const f32x4 z4 = {0.f, 0.f, 0.f, 0.f};
#pragma unroll
    for (int i = 0; i < 4; ++i)
#pragma unroll
        for (int j = 0; j < 4; ++j) acc[i][j] = z4;

    const int ar = t >> 2, ac = (t & 3) * 8;

    float4 A0a, A0b, A1a, A1b; uint4 B0, B1;
    auto loadTile = [&](int k0) {
        const float* Hs = ((k0 < 512) ? H4 : (k0 < 1024) ? H8 : H12) + hb;
        const int kc = (k0 & 511) + ac;
        const float* r0 = Hs + (size_t)(rowBase + ar) * E_ + kc;
        const float* r1 = r0 + (size_t)64 * E_;
        A0a = *(const float4*)r0;       A0b = *(const float4*)(r0 + 4);
        A1a = *(const float4*)r1;       A1b = *(const float4*)(r1 + 4);
        B0  = *(const uint4*)(W1c + (size_t)(colBase + ar) * CIN + k0 + ac);
        B1  = *(const uint4*)(W1c + (size_t)(colBase + ar + 64) * CIN + k0 + ac);
    };
    loadTile(0);

    for (int k0 = 0; k0 < CIN; k0 += 32) {
        __syncthreads();   // prev iteration's frag reads done
        *(uint4*)&Asm[ar * LDP + ac]        = cvt8(A0a, A0b);
        *(uint4*)&Asm[(ar + 64) * LDP + ac] = cvt8(A1a, A1b);
        *(uint4*)&Bsm[ar * LDP + ac]        = B0;
        *(uint4*)&Bsm[(ar + 64) * LDP + ac] = B1;
        __syncthreads();
        if (k0 + 32 < CIN) loadTile(k0 + 32);   // prefetch overlaps frag reads + MFMA

        s16x8 af[4], bfr[4];
#pragma unroll
        for (int mi = 0; mi < 4; ++mi)
            af[mi] = *(const s16x8*)&Asm[(wr * 64 + mi * 16 + l15) * LDP + quad * 8];
#pragma unroll
        for (int ni = 0; ni < 4; ++ni)
            bfr[ni] = *(const s16x8*)&Bsm[(wc * 64 + ni * 16 + l15) * LDP + quad * 8];
#pragma unroll
        for (int mi = 0; mi < 4; ++mi)
#pragma unroll
            for (int ni = 0; ni < 4; ++ni)
                acc[mi][ni] = __builtin_amdgcn_mfma_f32_16x16x32_bf16(
                    af[mi], bfr[ni], acc[mi][ni], 0, 0, 0);
    }

#pragma unroll
    for (int mi = 0; mi < 4; ++mi) {
        const int row0 = rowBase + wr * 64 + mi * 16 + quad * 4;
#pragma unroll
        for (int ni = 0; ni < 4; ++ni) {
            const int col = colBase + wc * 64 + ni * 16 + l15;
#pragma unroll
            for (int r = 0; r < 4; ++r)
                G[((size_t)bb * S_ + row0 + r) * OUTC + col] = acc[mi][ni][r];
        }
    }
}

// ---------- 3) blend: C1[p] = sum_k w_k * G[b,i_k] (fp32) -> bf16 + BN1 stats ----------
__global__ __launch_bounds__(256) void blend1(
    const float* __restrict__ G, const int* __restrict__ idx, const float* __restrict__ wgt,
    ushort_t* __restrict__ C1, float* __restrict__ gsum, float* __restrict__ gsq)
{
    __shared__ float reds[512], redq[512];
    const int t = threadIdx.x;
    const int cg = t & 63, pr = t >> 6;
    const int ch0 = cg * 8;
    const int pBase = blockIdx.x * 128;

    float s[8], q[8];
#pragma unroll
    for (int e = 0; e < 8; ++e) { s[e] = 0.f; q[e] = 0.f; }

    for (int j = 0; j < 32; ++j) {
        const int p = pBase + j * 4 + pr;
        const int b = p >> 13;
        const int i0 = idx[p * 3 + 0], i1 = idx[p * 3 + 1], i2 = idx[p * 3 + 2];
        const float w0 = wgt[p * 3 + 0], w1 = wgt[p * 3 + 1], w2 = wgt[p * 3 + 2];
        const float* g0 = G + ((size_t)b * S_ + i0) * OUTC + ch0;
        const float* g1 = G + ((size_t)b * S_ + i1) * OUTC + ch0;
        const float* g2 = G + ((size_t)b * S_ + i2) * OUTC + ch0;
        float c[8];
        uint32_t od[4];
#pragma unroll
        for (int e = 0; e < 8; ++e) {
            c[e] = w0 * g0[e] + w1 * g1[e] + w2 * g2[e];
            s[e] += c[e]; q[e] += c[e] * c[e];
        }
#pragma unroll
        for (int e = 0; e < 4; ++e) od[e] = f2b(c[2 * e]) | (f2b(c[2 * e + 1]) << 16);
        uint4 o; o.x = od[0]; o.y = od[1]; o.z = od[2]; o.w = od[3];
        *(uint4*)(C1 + (size_t)p * OUTC + ch0) = o;
    }

    for (int i = t; i < 512; i += 256) { reds[i] = 0.f; redq[i] = 0.f; }
    __syncthreads();
#pragma unroll
    for (int e = 0; e < 8; ++e) {
        atomicAdd(&reds[ch0 + e], s[e]);
        atomicAdd(&redq[ch0 + e], q[e]);
    }
    __syncthreads();
    for (int i = t; i < 512; i += 256) {
        atomicAdd(&gsum[i], reds[i]);
        atomicAdd(&gsq[i],  redq[i]);
    }
}

// ---------- 4) BN finalize (gamma/beta fp32 wire) ----------
__global__ void bn_finalize(const float* __restrict__ gsum, const float* __restrict__ gsq,
                            const float* __restrict__ gamma, const float* __restrict__ beta,
                            float* __restrict__ ss)
{
    const int c = threadIdx.x;   // 512
    const float inv  = 1.0f / (float)P_;
    const float mean = gsum[c] * inv;
    const float var  = gsq[c] * inv - mean * mean;
    const float sc   = gamma[c] * rsqrtf(var + 1e-5f);
    ss[c]       = sc;
    ss[512 + c] = beta[c] - mean * sc;
}

// ---------- 5) BN apply + ReLU on bf16 C1 (in place) ----------
__global__ __launch_bounds__(256) void bn_apply_c1(
    ushort_t* __restrict__ X, const float* __restrict__ ss)
{
    __shared__ float sc[512], sh[512];
    const int t = threadIdx.x;
    for (int i = t; i < 512; i += 256) { sc[i] = ss[i]; sh[i] = ss[512 + i]; }
    __syncthreads();
    const size_t v = (size_t)blockIdx.x * 256 + t;
    uint4 xv = ((const uint4*)X)[v];
    const int ch = (int)((v * 8) & 511);
    uint32_t wsrc[4] = {xv.x, xv.y, xv.z, xv.w};
    uint32_t od[4];
#pragma unroll
    for (int j = 0; j < 4; ++j) {
        const int c0 = ch + 2 * j;
        const float y0 = fmaxf(0.f, b2f(wsrc[j] & 0xffffu) * sc[c0]     + sh[c0]);
        const float y1 = fmaxf(0.f, b2f(wsrc[j] >> 16)     * sc[c0 + 1] + sh[c0 + 1]);
        od[j] = f2b(y0) | (f2b(y1) << 16);
    }
    uint4 o; o.x = od[0]; o.y = od[1]; o.z = od[2]; o.w = od[3];
    ((uint4*)X)[v] = o;
}

// ---------- 6) GEMM2 (m97 global_load_lds staging): C1 x W2c^T + BN2 stats ----------
// grid(256,4): x = row-tile (XCD pin x%8), y = col-tile -> A-tile fetched once per XCD.
__global__ __launch_bounds__(256) void gemm2_stats(
    const ushort_t* __restrict__ A, const ushort_t* __restrict__ Bw,
    float* __restrict__ outF, ushort_t* __restrict__ outB, int out_bf16,
    float* __restrict__ gsum, float* __restrict__ gsq)
{
    __shared__ __align__(16) ushort_t Asm[128 * 32];   // 8 KB, NO padding (DMA layout)
    __shared__ __align__(16) ushort_t Bsm[128 * 32];
    __shared__ float red[256];
    const int K = 512, Nn = 512;
    const int t = threadIdx.x, wave = t >> 6, lane = t & 63;
    const int wr = wave >> 1, wc = wave & 1, quad = lane >> 4, l15 = lane & 15;
    const int rowBase = blockIdx.x * 128, colBase = blockIdx.y * 128;

    f32x4 acc[4][4];
    const f32x4 z4 = {0.f, 0.f, 0.f, 0.f};
#pragma unroll
    for (int i = 0; i < 4; ++i)
#pragma unroll
        for (int j = 0; j < 4; ++j) acc[i][j] = z4;

    // slot s = t (and t+256): row = s>>2, 16B-chunk = s&3; LDS dst = s*16B (lane-contig)
    const int ar0 = t >> 2, ac0 = (t & 3) * 8;
    const int ar1 = ar0 + 64;
    const ushort_t* Ab = A  + (size_t)rowBase * K;
    const ushort_t* Bb = Bw + (size_t)colBase * K;

    for (int k0 = 0; k0 < K; k0 += 32) {
        async16(Ab + (size_t)ar0 * K + k0 + ac0, &Asm[(size_t)t * 8]);
        async16(Ab + (size_t)ar1 * K + k0 + ac0, &Asm[(size_t)(t + 256) * 8]);
        async16(Bb + (size_t)ar0 * K + k0 + ac0, &Bsm[(size_t)t * 8]);
        async16(Bb + (size_t)ar1 * K + k0 + ac0, &Bsm[(size_t)(t + 256) * 8]);
        __syncthreads();   // vmcnt(0) drain -> tiles visible

        s16x8 af[4], bfr[4];
#pragma unroll
        for (int mi = 0; mi < 4; ++mi)
            af[mi] = *(const s16x8*)&Asm[(wr * 64 + mi * 16 + l15) * 32 + quad * 8];
#pragma unroll
        for (int ni = 0; ni < 4; ++ni)
            bfr[ni] = *(const s16x8*)&Bsm[(wc * 64 + ni * 16 + l15) * 32 + quad * 8];
#pragma unroll
        for (int mi = 0; mi < 4; ++mi)
#pragma unroll
            for (int ni = 0; ni < 4; ++ni)
                acc[mi][ni] = __builtin_amdgcn_mfma_f32_16x16x32_bf16(
                    af[mi], bfr[ni], acc[mi][ni], 0, 0, 0);
        __syncthreads();   // reads done before next DMA overwrites
    }

    // BN2 stats
    red[t] = 0.f;
    __syncthreads();
#pragma unroll
    for (int ni = 0; ni < 4; ++ni) {
        float s = 0.f, q = 0.f;
#pragma unroll
        for (int mi = 0; mi < 4; ++mi)
#pragma unroll
            for (int r = 0; r < 4; ++r) { const float v = acc[mi][ni][r]; s += v; q += v * v; }
        const int cl = wc * 64 + ni * 16 + l15;
        atomicAdd(&red[cl], s);
        atomicAdd(&red[128 + cl], q);
    }
    __syncthreads();
    if (t < 128) atomicAdd(&gsum[colBase + t], red[t]);
    else         atomicAdd(&gsq[colBase + (t - 128)], red[t]);

    // store. D layout: col(N)=lane&15, row(M)=quad*4+reg
    if (out_bf16) {
#pragma unroll
        for (int mi = 0; mi < 4; ++mi) {
            const int row0 = rowBase + wr * 64 + mi * 16 + quad * 4;
#pragma unroll
            for (int ni = 0; ni < 4; ++ni) {
                const int col = colBase + wc * 64 + ni * 16 + l15;
#pragma unroll
                for (int r = 0; r < 4; ++r)
                    outB[(size_t)(row0 + r) * Nn + col] = (ushort_t)f2b(acc[mi][ni][r]);
            }
        }
    } else {
#pragma unroll
        for (int mi = 0; mi < 4; ++mi) {
            const int row0 = rowBase + wr * 64 + mi * 16 + quad * 4;
#pragma unroll
            for (int ni = 0; ni < 4; ++ni) {
                const int col = colBase + wc * 64 + ni * 16 + l15;
#pragma unroll
                for (int r = 0; r < 4; ++r)
                    outF[(size_t)(row0 + r) * Nn + col] = acc[mi][ni][r];
            }
        }
    }
}

// ---------- 7) BN2 apply + ReLU -> d_out fp32 ----------
__global__ __launch_bounds__(256) void bn_apply_out(
    const ushort_t* __restrict__ C2, float* __restrict__ Y,
    const float* __restrict__ ss, int from_bf16)
{
    __shared__ float sc[512], sh[512];
    const int t = threadIdx.x;
    for (int i = t; i < 512; i += 256) { sc[i] = ss[i]; sh[i] = ss[512 + i]; }
    __syncthreads();
    const size_t v = (size_t)blockIdx.x * 256 + t;   // 8 elems/thread
    const int ch = (int)((v * 8) & 511);
    float4 u0, u1;
    if (from_bf16) {
        const uint4 xv = ((const uint4*)C2)[v];
        u0.x = b2f(xv.x & 0xffffu); u0.y = b2f(xv.x >> 16);
        u0.z = b2f(xv.y & 0xffffu); u0.w = b2f(xv.y >> 16);
        u1.x = b2f(xv.z & 0xffffu); u1.y = b2f(xv.z >> 16);
        u1.z = b2f(xv.w & 0xffffu); u1.w = b2f(xv.w >> 16);
    } else {
        u0 = ((const float4*)Y)[v * 2];
        u1 = ((const float4*)Y)[v * 2 + 1];
    }
    u0.x = fmaxf(0.f, u0.x * sc[ch + 0] + sh[ch + 0]);
    u0.y = fmaxf(0.f, u0.y * sc[ch + 1] + sh[ch + 1]);
    u0.z = fmaxf(0.f, u0.z * sc[ch + 2] + sh[ch + 2]);
    u0.w = fmaxf(0.f, u0.w * sc[ch + 3] + sh[ch + 3]);
    u1.x = fmaxf(0.f, u1.x * sc[ch + 4] + sh[ch + 4]);
    u1.y = fmaxf(0.f, u1.y * sc[ch + 5] + sh[ch + 5]);
    u1.z = fmaxf(0.f, u1.z * sc[ch + 6] + sh[ch + 6]);
    u1.w = fmaxf(0.f, u1.w * sc[ch + 7] + sh[ch + 7]);
    ((float4*)Y)[v * 2]     = u0;
    ((float4*)Y)[v * 2 + 1] = u1;
}

// ---------- launch ----------
extern "C" void kernel_launch(void* const* d_in, const int* in_sizes, int n_in,
                              void* d_out, int out_size, void* d_ws, size_t ws_size,
                              hipStream_t stream)
{
    (void)in_sizes; (void)n_in; (void)out_size;
    // fp32 wire (reference is float32 end-to-end; confirmed by WRITE_SIZE = 67 MB)
    const float* xyzF = (const float*)d_in[0];
    const float* cenF = (const float*)d_in[1];
    const float* H4   = (const float*)d_in[2];
    const float* H8   = (const float*)d_in[3];
    const float* H12  = (const float*)d_in[4];
    const float* W1f  = (const float*)d_in[5];
    // b1 (d_in[6]) / b2 (d_in[10]) cancel in BN mean subtraction
    const float* g1F  = (const float*)d_in[7];
    const float* be1F = (const float*)d_in[8];
    const float* W2f  = (const float*)d_in[9];
    const float* g2F  = (const float*)d_in[11];
    const float* be2F = (const float*)d_in[12];

    char* w = (char*)d_ws;
    float*    stats = (float*)w;     w += 2048 * 4;
    float*    ss1   = (float*)w;     w += 1024 * 4;
    float*    ss2   = (float*)w;     w += 1024 * 4;
    ushort_t* W1c   = (ushort_t*)w;  w += (size_t)OUTC * CIN * 2;
    ushort_t* W2c   = (ushort_t*)w;  w += (size_t)OUTC * OUTC * 2;
    int*      idxb  = (int*)w;       w += (size_t)P_ * 3 * 4;
    float*    wb    = (float*)w;     w += (size_t)P_ * 3 * 4;
    float*    G     = (float*)w;     w += (size_t)4 * S_ * OUTC * 4;   // 4 MB
    ushort_t* C1    = (ushort_t*)w;  w += (size_t)P_ * OUTC * 2;       // 32 MB
    const size_t need1 = (size_t)(w - (char*)d_ws);
    const int out_bf16 = (ws_size >= need1 + (size_t)P_ * OUTC * 2) ? 1 : 0;
    ushort_t* C2 = (ushort_t*)w;     // only used when out_bf16
    float* sum1 = stats, *sq1 = stats + 512, *sum2 = stats + 1024, *sq2 = stats + 1536;

    hipMemsetAsync(stats, 0, 2048 * 4, stream);
    prep_w<<<(OUTC * CIN / 4 + OUTC * OUTC / 4) / 256, 256, 0, stream>>>(W1f, W2f, W1c, W2c);
    knn_kernel<<<P_ / 128, 128, 0, stream>>>(xyzF, cenF, idxb, wb);
    gemm_g<<<dim3(4, 4, 4), 256, 0, stream>>>(H4, H8, H12, W1c, G);
    blend1<<<P_ / 128, 256, 0, stream>>>(G, idxb, wb, C1, sum1, sq1);
    bn_finalize<<<1, 512, 0, stream>>>(sum1, sq1, g1F, be1F, ss1);
    bn_apply_c1<<<(P_ * OUTC / 8) / 256, 256, 0, stream>>>(C1, ss1);
    gemm2_stats<<<dim3(P_ / 128, 4), 256, 0, stream>>>(C1, W2c, (float*)d_out, C2,
                                                       out_bf16, sum2, sq2);
    bn_finalize<<<1, 512, 0, stream>>>(sum2, sq2, g2F, be2F, ss2);
    bn_apply_out<<<(P_ * OUTC / 8) / 256, 256, 0, stream>>>(C2, (float*)d_out, ss2, out_bf16);
}